// Round 17
// baseline (66.696 us; speedup 1.0000x reference)
//
#include <hip/hip_runtime.h>
#include <hip/hip_bf16.h>

// TinyAttention fused pipeline, bf16 MFMA path.
// Round 17: k_qkv x-staging via __builtin_amdgcn_global_load_lds (width 16).
// Every prior variant staged x global->VGPR->cvt->ds_write: the staging wave
// blocks on an s_waitcnt for the load return in-line every step (and FIFO
// vmcnt retires deep prefetches early via the W-register waits), which is why
// occupancy/depth/barrier changes were all null. DMA staging has NO register
// dependency: only a counted vmcnt(16) at the barrier, two regions later.
// LDS dest linear (required); XOR swizzle (p = g ^ (row&15)) applied on the
// GLOBAL source so compute-side f32 ds_reads are conflict-free (T21).
// f32->bf16 conversion moves to the consumer (VALU was 90% idle).
// k_prep / k_attn / k_out identical to round 16.
// ws layout (bytes):
//   Qf  bf16 [8][64][4][2][32][8]    @ 0         (2,097,152)  (q pre-scaled)
//   Kf  bf16 [8][64][4][2][32][8]    @ 2,097,152 (2,097,152)
//   Vf  bf16 [8][64][2][2][2][32][8] @ 4,194,304 (2,097,152)
//   att bf16 [16384][64]             @ 6,291,456 (2,097,152)
//   Wtf bf16 [24][4][6][64][8]       @ 8,388,608 (589,824)   (frag-native)
//   WtO bf16 [768][64]               @ 8,978,432 (98,304)

typedef __attribute__((ext_vector_type(8))) short short8;
typedef __attribute__((ext_vector_type(4))) short short4v;
typedef __attribute__((ext_vector_type(4))) float float4v;
typedef __attribute__((ext_vector_type(16))) float float16v;

#define MFMA16(a, b, c) __builtin_amdgcn_mfma_f32_16x16x32_bf16((a), (b), (c), 0, 0, 0)
#define MFMA32(a, b, c) __builtin_amdgcn_mfma_f32_32x32x16_bf16((a), (b), (c), 0, 0, 0)

// LDS-only barrier (epilogue): orders ds ops without draining vmcnt.
#define LDS_BARRIER() asm volatile("s_waitcnt lgkmcnt(0)\n\ts_barrier" ::: "memory")
// Main-loop barrier: allow the 2 newest regions' 16 vm ops to stay in flight;
// forces the 2-region-old DMA pair (the buffer read next step) to completion.
#define BAR_VM16() asm volatile("s_waitcnt vmcnt(16) lgkmcnt(0)\n\ts_barrier" ::: "memory")
#define BAR_VM0()  asm volatile("s_waitcnt vmcnt(0) lgkmcnt(0)\n\ts_barrier" ::: "memory")

// async global->LDS DMA, 16B per lane; LDS dest is wave-uniform base+lane*16.
static __device__ __forceinline__ void gload_lds16(const float* g, float* l) {
  __builtin_amdgcn_global_load_lds(
      (const __attribute__((address_space(1))) void*)g,
      (__attribute__((address_space(3))) void*)l, 16, 0, 0);
}

// v_permlane32_swap_b32 a, b:  a[32+i] <-> b[i]  (VALU cross-lane, no DS)
static __device__ __forceinline__ void plswap(unsigned& a, unsigned& b) {
  asm("v_permlane32_swap_b32 %0, %1" : "+v"(a), "+v"(b));
}

static __device__ __forceinline__ unsigned short f2bf(float x) {
  union { float f; unsigned u; } v; v.f = x;
  return (unsigned short)((v.u + 0x7FFFu + ((v.u >> 16) & 1u)) >> 16);
}
static __device__ __forceinline__ short8 cvt8(float4v a, float4v b) {
  short8 s;
#pragma unroll
  for (int j = 0; j < 4; ++j) { s[j] = (short)f2bf(a[j]); s[j + 4] = (short)f2bf(b[j]); }
  return s;
}
static __device__ __forceinline__ short8 ldg8(const short* p) {
  return *(const short8*)p;
}

// ---------------------------------------------------------------------------
// k_prep:
//  blocks 0..95 : W_qkv f32 [1536][192] -> Wtf bf16 fragment-native
//  blocks 96..107: W_out f32 [64][768] -> WtO bf16 [768][64]
// ---------------------------------------------------------------------------
__global__ __launch_bounds__(256) void k_prep(
    const float* __restrict__ Wq, const float* __restrict__ Wo,
    short* __restrict__ Wtf, short* __restrict__ WtO) {
  __shared__ float wl[64 * 52];
  __shared__ __align__(16) short tl[64 * 72];
  const int tid = threadIdx.x;
  int id = blockIdx.x;
  if (id < 96) {
    const int kk = id >> 2, w = id & 3;
    const int r = tid >> 2, cq = (tid & 3) * 12;
    const float* sp = Wq + (size_t)(kk * 64 + r) * 192 + w * 48 + cq;
    float4v a = *(const float4v*)(sp);
    float4v b = *(const float4v*)(sp + 4);
    float4v c4 = *(const float4v*)(sp + 8);
    float* dp = wl + r * 52 + cq;
    *(float4v*)(dp) = a; *(float4v*)(dp + 4) = b; *(float4v*)(dp + 8) = c4;
    __syncthreads();
#pragma unroll
    for (int i = 0; i < 2; ++i) {
      const int fid = i * 256 + tid;
      if (fid < 384) {
        const int frag = fid >> 6, lane = fid & 63;
        const int lo = lane & 15, hi = lane >> 4;
        const int c = frag >> 1, ks = frag & 1;
        short8 o;
#pragma unroll
        for (int e = 0; e < 8; ++e)
          o[e] = (short)f2bf(wl[(ks * 32 + hi * 8 + e) * 52 + c * 16 + lo]);
        *(short8*)(Wtf + ((((size_t)kk * 4 + w) * 6 + frag) << 9) + lane * 8) = o;
      }
    }
  } else {
    id -= 96;
    const int r = tid >> 2, cq = (tid & 3) * 16;
    const float* sp = Wo + (size_t)r * 768 + id * 64 + cq;
    float4v v0 = *(const float4v*)(sp);
    float4v v1 = *(const float4v*)(sp + 4);
    float4v v2 = *(const float4v*)(sp + 8);
    float4v v3 = *(const float4v*)(sp + 12);
    short8 s0, s1;
#pragma unroll
    for (int i = 0; i < 4; ++i) {
      s0[i] = (short)f2bf(v0[i]); s0[i + 4] = (short)f2bf(v1[i]);
      s1[i] = (short)f2bf(v2[i]); s1[i + 4] = (short)f2bf(v3[i]);
    }
    *(short8*)(tl + r * 72 + cq) = s0;
    *(short8*)(tl + r * 72 + cq + 8) = s1;
    __syncthreads();
    short8 o0, o1;
#pragma unroll
    for (int j = 0; j < 8; ++j) {
      o0[j] = tl[(cq + j) * 72 + r];
      o1[j] = tl[(cq + 8 + j) * 72 + r];
    }
    short* dp2 = WtO + (size_t)(id * 64 + r) * 64 + cq;
    *(short8*)(dp2) = o0;
    *(short8*)(dp2 + 8) = o1;
  }
}

// ---------------------------------------------------------------------------
// k_qkv: qkv = x @ W_qkv + b; writes fragment-native Qf/Kf/Vf (coalesced).
// 512 blocks x 256 thr (4 waves): block = 32 rows x 192 cols, wave = 32r x 48c.
// x staged f32 via global_load_lds into 4 swizzled LDS buffers; W 2-set
// register rolling prefetch; counted-vmcnt barriers; cvt on consumer side.
// ---------------------------------------------------------------------------
__global__ __launch_bounds__(256) void k_qkv(
    const float* __restrict__ x, const short* __restrict__ Wtf,
    const float* __restrict__ bq, short* __restrict__ Qf,
    short* __restrict__ Kf, short* __restrict__ Vf) {
  __shared__ __align__(16) float xf[4][32 * 64];   // 32 KB; epilogue reuses
  const int tid = threadIdx.x;
  const int w = tid >> 6, lane = tid & 63, lo = lane & 15, hi = lane >> 4;
  const int m0 = blockIdx.x * 32;
  const float KSC = 0.18033688011112042f;  // (1/8) * log2(e)
  const int cb = w * 48;

  float4v acc[2][3];
#pragma unroll
  for (int r = 0; r < 2; ++r)
#pragma unroll
    for (int c = 0; c < 3; ++c) acc[r][c] = (float4v)0.0f;

  // W-frag base: frag (kk, f) at wbase + kk*12288 + f*512
  const short* wbase = Wtf + ((size_t)w * 6) * 512 + lane * 8;
  short8 wA[6], wB[6];

  // DMA: wave w stages rows [8w, 8w+8) of the 32x64 f32 tile (2 x 1KB instr).
  // Lane l of instr j: LDS slot = row r=8w+4j+(l>>4), granule p=l&15 (linear);
  // fetches global granule g = p ^ (r&15)  (source-side swizzle).
#define DMA(KK, B)                                                             \
  do {                                                                         \
    _Pragma("unroll")                                                          \
    for (int _j = 0; _j < 2; ++_j) {                                           \
      const int _r = 8 * w + 4 * _j + (lane >> 4);                             \
      const int _g = (lane & 15) ^ (_r & 15);                                  \
      gload_lds16(x + (size_t)(m0 + _r) * 1536 + (KK) * 64 + _g * 4,           \
                  &xf[B][(8 * w + 4 * _j) * 64]);                              \
    }                                                                          \
  } while (0)

#define ISSUE_W(KK, WS)                                                        \
  do { const short* _wp = wbase + (size_t)(KK) * 12288;                        \
       _Pragma("unroll")                                                       \
       for (int _f = 0; _f < 6; ++_f) WS[_f] = ldg8(_wp + _f * 512); } while (0)

  // Read fragment granules with matching swizzle: granule gk of row is at
  // p = gk ^ (row & 15) = gk ^ lo.
#define COMPUTE(B, WS)                                                         \
  do { const float* _xb = &xf[B][0];                                           \
    _Pragma("unroll")                                                          \
    for (int _r = 0; _r < 2; ++_r) {                                           \
      const float* _rp = _xb + (_r * 16 + lo) * 64;                            \
      float4v _g0 = *(const float4v*)(_rp + ((2 * hi) ^ lo) * 4);              \
      float4v _g1 = *(const float4v*)(_rp + ((2 * hi + 1) ^ lo) * 4);          \
      float4v _g2 = *(const float4v*)(_rp + ((8 + 2 * hi) ^ lo) * 4);          \
      float4v _g3 = *(const float4v*)(_rp + ((8 + 2 * hi + 1) ^ lo) * 4);      \
      short8 _a0 = cvt8(_g0, _g1);                                             \
      short8 _a1 = cvt8(_g2, _g3);                                             \
      _Pragma("unroll")                                                        \
      for (int _c = 0; _c < 3; ++_c) {                                         \
        acc[_r][_c] = MFMA16(_a0, WS[2 * _c], acc[_r][_c]);                    \
        acc[_r][_c] = MFMA16(_a1, WS[2 * _c + 1], acc[_r][_c]);                \
      }                                                                        \
    } } while (0)

  // prologue: buffers 0..2 in flight via DMA, W(0)/W(1) in regs; full drain.
  DMA(0, 0);
  DMA(1, 1);
  DMA(2, 2);
  ISSUE_W(0, wA);
  ISSUE_W(1, wB);
  BAR_VM0();

  // main: kk = 0..19 (5 x unroll-4); all issue conditions always true.
  for (int k4 = 0; k4 < 20; k4 += 4) {
    COMPUTE(0, wA); ISSUE_W(k4 + 2, wA); DMA(k4 + 3, 3); BAR_VM16();
    COMPUTE(1, wB); ISSUE_W(k4 + 3, wB); DMA(k4 + 4, 0); BAR_VM16();
    COMPUTE(2, wA); ISSUE_W(k4 + 4, wA); DMA(k4 + 5, 1); BAR_VM16();
    COMPUTE(3, wB); ISSUE_W(k4 + 5, wB); DMA(k4 + 6, 2); BAR_VM16();
  }
  // tail: kk = 20..23, draining barriers.
  COMPUTE(0, wA); ISSUE_W(22, wA); DMA(23, 3); BAR_VM0();
  COMPUTE(1, wB); ISSUE_W(23, wB); BAR_VM0();
  COMPUTE(2, wA); BAR_VM0();
  COMPUTE(3, wB); BAR_VM0();
#undef DMA
#undef ISSUE_W
#undef COMPUTE

  float bb[3];
#pragma unroll
  for (int c = 0; c < 3; ++c) bb[c] = bq[cb + c * 16 + lo];

  const int b = m0 >> 11;
  const int row0 = m0 & 2047;  // batch-local 32-aligned row of block start
  short* sbase = (short*)&xf[0][0];  // reuse DMA buffers (drained + synced)
  short* qbuf = sbase;
  short* kstg = sbase + 2304;
  short* vstg = sbase + 4608;

#pragma unroll
  for (int r = 0; r < 2; ++r)
#pragma unroll
    for (int c = 0; c < 3; ++c) {
      const int colb = cb + c * 16;
      short* buf = (colb < 64) ? qbuf : ((colb < 128) ? kstg : vstg);
      const int d0 = (colb & 63) + lo;
#pragma unroll
      for (int j = 0; j < 4; ++j) {
        float vv = acc[r][c][j] + bb[c];
        if (colb < 64) vv *= KSC;  // q: fold softmax scale (exp2 domain)
        buf[(r * 16 + hi * 4 + j) * 72 + d0] = (short)f2bf(vv);
      }
    }
  LDS_BARRIER();

  // Q/K fragment stores: thread = (row rr 0..31, 8-d group dq)
  {
    const int rr = tid >> 3, dq = (tid & 7) * 8;
    const int t32 = row0 >> 5, i = dq >> 4, h = (dq >> 3) & 1;
    const size_t base = ((((size_t)b * 64 + t32) * 4 + i) * 2 + h) * 256 + rr * 8;
    *(short8*)(Qf + base) = *(const short8*)(qbuf + rr * 72 + dq);
    *(short8*)(Kf + base) = *(const short8*)(kstg + rr * 72 + dq);
  }

  // V fragment store: thread = (d=dr 0..63, 8-key group kq8), LDS transpose
  {
    const int dr = tid >> 2, kq8 = (tid & 3) * 8;
    short8 o0;
#pragma unroll
    for (int j = 0; j < 8; ++j) o0[j] = vstg[(kq8 + j) * 72 + dr];
    const int kg = row0 >> 5, s = (kq8 >> 4) & 1, h = (kq8 >> 3) & 1;
    const int dc = dr >> 5, c32 = dr & 31;
    short* vp = Vf + ((((((size_t)b * 64 + kg) * 2 + dc) * 2 + s) * 2 + h) * 32 + c32) * 8;
    *(short8*)(vp) = o0;
  }
}

// ---------------------------------------------------------------------------
// k_attn: in-block split-K flash attn. 512 blocks x 512 thr (8 waves).
// ---------------------------------------------------------------------------
__global__ __launch_bounds__(512) void k_attn(
    const short* __restrict__ Qf, const short* __restrict__ Kf,
    const short* __restrict__ Vf, short* __restrict__ att) {
  __shared__ float Od[8][32][76];
  __shared__ float Ol[8][32];
  const int tid = threadIdx.x;
  const int w = tid >> 6, lane = tid & 63;
  const int c = lane & 31, h = lane >> 5;
  const int b = blockIdx.x >> 6;
  const int qg = blockIdx.x & 63;
  const size_t g0 = (size_t)b * 2048 + qg * 32;

  short8 qf0 = ldg8(Qf + (((size_t)b * 64 + qg) * 4 + 0) * 512 + lane * 8);
  short8 qf1 = ldg8(Qf + (((size_t)b * 64 + qg) * 4 + 1) * 512 + lane * 8);
  short8 qf2 = ldg8(Qf + (((size_t)b * 64 + qg) * 4 + 2) * 512 + lane * 8);
  short8 qf3 = ldg8(Qf + (((size_t)b * 64 + qg) * 4 + 3) * 512 + lane * 8);

  float lp = 0.0f;
  float16v acc0 = (float16v)0.0f;   // O^T d 0..31
  float16v acc1 = (float16v)0.0f;   // O^T d 32..63

  int kg = w * 8;                   // 8 subtiles of 32 keys = 256 keys/wave
  const short* kb = Kf + ((size_t)b * 64) * 2048 + lane * 8;
  const short* vb = Vf + ((size_t)b * 64) * 2048 + lane * 8;

#define ATTN_STEP(K0, K1, K2, K3, V0, V1, V2, V3)                              \
  do {                                                                         \
    float16v sf = (float16v)0.0f;                                              \
    sf = MFMA32(K0, qf0, sf);                                                  \
    sf = MFMA32(K1, qf1, sf);                                                  \
    sf = MFMA32(K2, qf2, sf);                                                  \
    sf = MFMA32(K3, qf3, sf);                                                  \
    unsigned wpk[8];                                                           \
    _Pragma("unroll")                                                          \
    for (int m = 0; m < 8; ++m) {                                              \
      float p0 = __builtin_amdgcn_exp2f(sf[2 * m]);                            \
      float p1 = __builtin_amdgcn_exp2f(sf[2 * m + 1]);                        \
      unsigned u0 = __builtin_bit_cast(unsigned, p0) & 0xFFFF0000u;            \
      unsigned u1 = __builtin_bit_cast(unsigned, p1) & 0xFFFF0000u;            \
      lp += __builtin_bit_cast(float, u0) + __builtin_bit_cast(float, u1);     \
      wpk[m] = (u0 >> 16) | u1;                                                \
    }                                                                          \
    plswap(wpk[0], wpk[2]);                                                    \
    plswap(wpk[1], wpk[3]);                                                    \
    plswap(wpk[4], wpk[6]);                                                    \
    plswap(wpk[5], wpk[7]);                                                    \
    union { unsigned u[4]; short8 s8; } bt0, bt1;                              \
    bt0.u[0] = wpk[0]; bt0.u[1] = wpk[1]; bt0.u[2] = wpk[2]; bt0.u[3] = wpk[3];\
    bt1.u[0] = wpk[4]; bt1.u[1] = wpk[5]; bt1.u[2] = wpk[6]; bt1.u[3] = wpk[7];\
    acc0 = MFMA32(V0, bt0.s8, acc0);                                           \
    acc0 = MFMA32(V1, bt1.s8, acc0);                                           \
    acc1 = MFMA32(V2, bt0.s8, acc1);                                           \
    acc1 = MFMA32(V3, bt1.s8, acc1);                                           \
  } while (0)

  const short* kpA = kb + (size_t)kg * 2048;
  const short* vpA = vb + (size_t)kg * 2048;
  short8 ka0 = ldg8(kpA), ka1 = ldg8(kpA + 512), ka2 = ldg8(kpA + 1024), ka3 = ldg8(kpA + 1536);
  short8 va0 = ldg8(vpA), va1 = ldg8(vpA + 512), va2 = ldg8(vpA + 1024), va3 = ldg8(vpA + 1536);

  for (int t = 0; t < 8; t += 2) {
    const short* kpB = kb + (size_t)(kg + 1) * 2048;
    const short* vpB = vb + (size_t)(kg + 1) * 2048;
    short8 kb0 = ldg8(kpB), kb1 = ldg8(kpB + 512), kb2 = ldg8(kpB + 1024), kb3 = ldg8(kpB + 1536);
    short8 vb0 = ldg8(vpB), vb1 = ldg8(vpB + 512), vb2 = ldg8(vpB + 1024), vb3 = ldg8(vpB + 1536);

    ATTN_STEP(ka0, ka1, ka2, ka3, va0, va1, va2, va3);

    if (t + 2 < 8) {
      const short* kpN = kb + (size_t)(kg + 2) * 2048;
      const short* vpN = vb + (size_t)(kg + 2) * 2048;
      ka0 = ldg8(kpN); ka1 = ldg8(kpN + 512); ka2 = ldg8(kpN + 1024); ka3 = ldg8(kpN + 1536);
      va0 = ldg8(vpN); va1 = ldg8(vpN + 512); va2 = ldg8(vpN + 1024); va3 = ldg8(vpN + 1536);
    }

    ATTN_STEP(kb0, kb1, kb2, kb3, vb0, vb1, vb2, vb3);
    kg += 2;
  }
#undef ATTN_STEP

  lp += __shfl_xor(lp, 32, 64);

#pragma unroll
  for (int g = 0; g < 4; ++g) {
    float4v a0, a1;
#pragma unroll
    for (int r = 0; r < 4; ++r) { a0[r] = acc0[4 * g + r]; a1[r] = acc1[4 * g + r]; }
    *(float4v*)(&Od[w][c][8 * g + 4 * h]) = a0;
    *(float4v*)(&Od[w][c][32 + 8 * g + 4 * h]) = a1;
  }
  if (h == 0) Ol[w][c] = lp;
  __syncthreads();

  {
    const int q = tid >> 4, dq = (tid & 15) * 4;
    float L = 0.0f;
    float4v o = (float4v)0.0f;
#pragma unroll
    for (int w2 = 0; w2 < 8; ++w2) {
      L += Ol[w2][q];
      o += *(const float4v*)(&Od[w2][q][dq]);
    }
    const float inv = 1.0f / L;
    short4v r;
#pragma unroll
    for (int j = 0; j < 4; ++j) r[j] = (short)f2bf(o[j] * inv);
    *(short4v*)(att + (g0 + q) * 64 + dq) = r;
  }
}

// ---------------------------------------------------------------------------
// k_out: out = att @ W_out + b_out (fp32 out). 512 blocks x 256 thr (4 waves).
// ---------------------------------------------------------------------------
__global__ __launch_bounds__(256) void k_out(
    const short* __restrict__ att, const short* __restrict__ WtO,
    const float* __restrict__ bo, float* __restrict__ out) {
  const int tid = threadIdx.x;
  const int w = tid >> 6, lane = tid & 63, lo = lane & 15, hi = lane >> 4;
  const int wc = w * 192;
  const int m0 = blockIdx.x * 32;

  short8 af[2][2];
#pragma unroll
  for (int rf = 0; rf < 2; ++rf) {
    const short* ap = att + (size_t)(m0 + rf * 16 + lo) * 64 + hi * 8;
    af[rf][0] = ldg8(ap);
    af[rf][1] = ldg8(ap + 32);
  }
  float4v acc[2][12];
#pragma unroll
  for (int rf = 0; rf < 2; ++rf)
#pragma unroll
    for (int c = 0; c < 12; ++c) acc[rf][c] = (float4v)0.0f;

#pragma unroll
  for (int c = 0; c < 12; ++c) {
    const short* bp = WtO + (size_t)(wc + c * 16 + lo) * 64 + hi * 8;
    short8 b0 = ldg8(bp);
    short8 b1 = ldg8(bp + 32);
#pragma unroll
    for (int rf = 0; rf < 2; ++rf) {
      acc[rf][c] = MFMA16(af[rf][0], b0, acc[rf][c]);
      acc[rf][c] = MFMA16(af[rf][1], b1, acc[rf][c]);
    }
  }
#pragma unroll
  for (int c = 0; c < 12; ++c) {
    const float bb = bo[wc + c * 16 + lo];
#pragma unroll
    for (int rf = 0; rf < 2; ++rf)
#pragma unroll
      for (int j = 0; j < 4; ++j)
        out[(size_t)(m0 + rf * 16 + hi * 4 + j) * 768 + wc + c * 16 + lo] =
            acc[rf][c][j] + bb;
  }
}

extern "C" void kernel_launch(void* const* d_in, const int* in_sizes, int n_in,
                              void* d_out, int out_size, void* d_ws, size_t ws_size,
                              hipStream_t stream) {
  (void)in_sizes; (void)n_in; (void)out_size; (void)ws_size;
  const float* x  = (const float*)d_in[0];
  const float* Wq = (const float*)d_in[1];
  const float* bq = (const float*)d_in[2];
  const float* Wo = (const float*)d_in[3];
  const float* bo = (const float*)d_in[4];
  float* out = (float*)d_out;

  char* ws = (char*)d_ws;
  short* Qf  = (short*)(ws);
  short* Kf  = (short*)(ws + 2097152);
  short* Vf  = (short*)(ws + 4194304);
  short* att = (short*)(ws + 6291456);
  short* Wtf = (short*)(ws + 8388608);
  short* WtO = (short*)(ws + 8978432);

  k_prep<<<108, 256, 0, stream>>>(Wq, Wo, Wtf, WtO);
  k_qkv<<<512, 256, 0, stream>>>(x, Wtf, bq, Qf, Kf, Vf);
  k_attn<<<512, 512, 0, stream>>>(Qf, Kf, Vf, att);
  k_out<<<512, 256, 0, stream>>>(att, WtO, bo, out);
}

// Round 18
// 63.459 us; speedup vs baseline: 1.0510x; 1.0510x over previous
//
#include <hip/hip_runtime.h>
#include <hip/hip_bf16.h>

// TinyAttention fused pipeline, bf16 MFMA path.
// Round 18: de-phased shared-operand sweeps. In every prior variant all
// blocks read the SAME W / K/V / WtO lines in the SAME order at the same
// time -> identical-address storms serialize on a few L2 slices (the model
// that finally reproduces k_qkv's invariant ~41us across 9 structural
// changes). Fix costs nothing structural: rotate each block's iteration
// order (k_qkv K-loop by blockIdx%24, k_attn subtiles by qg&7, k_out columns
// by blockIdx%12) so concurrent reads spread across slices. Accumulation is
// order-invariant. Everything else identical to round 15 (61.8us best).
// ws layout (bytes):
//   Qf  bf16 [8][64][4][2][32][8]    @ 0         (2,097,152)  (q pre-scaled)
//   Kf  bf16 [8][64][4][2][32][8]    @ 2,097,152 (2,097,152)
//   Vf  bf16 [8][64][2][2][2][32][8] @ 4,194,304 (2,097,152)
//   att bf16 [16384][64]             @ 6,291,456 (2,097,152)
//   Wtf bf16 [24][4][6][64][8]       @ 8,388,608 (589,824)   (frag-native)
//   WtO bf16 [768][64]               @ 8,978,432 (98,304)

typedef __attribute__((ext_vector_type(8))) short short8;
typedef __attribute__((ext_vector_type(4))) short short4v;
typedef __attribute__((ext_vector_type(4))) float float4v;
typedef __attribute__((ext_vector_type(16))) float float16v;

#define MFMA16(a, b, c) __builtin_amdgcn_mfma_f32_16x16x32_bf16((a), (b), (c), 0, 0, 0)
#define MFMA32(a, b, c) __builtin_amdgcn_mfma_f32_32x32x16_bf16((a), (b), (c), 0, 0, 0)

// LDS-only barrier: orders ds ops across the block without draining vmcnt.
#define LDS_BARRIER() asm volatile("s_waitcnt lgkmcnt(0)\n\ts_barrier" ::: "memory")

// v_permlane32_swap_b32 a, b:  a[32+i] <-> b[i]  (VALU cross-lane, no DS)
static __device__ __forceinline__ void plswap(unsigned& a, unsigned& b) {
  asm("v_permlane32_swap_b32 %0, %1" : "+v"(a), "+v"(b));
}

static __device__ __forceinline__ unsigned short f2bf(float x) {
  union { float f; unsigned u; } v; v.f = x;
  return (unsigned short)((v.u + 0x7FFFu + ((v.u >> 16) & 1u)) >> 16);
}
static __device__ __forceinline__ short8 ldg8(const short* p) {
  return *(const short8*)p;
}

// ---------------------------------------------------------------------------
// k_prep:
//  blocks 0..95 : W_qkv f32 [1536][192] -> Wtf bf16 fragment-native
//  blocks 96..107: W_out f32 [64][768] -> WtO bf16 [768][64]
// ---------------------------------------------------------------------------
__global__ __launch_bounds__(256) void k_prep(
    const float* __restrict__ Wq, const float* __restrict__ Wo,
    short* __restrict__ Wtf, short* __restrict__ WtO) {
  __shared__ float wl[64 * 52];
  __shared__ __align__(16) short tl[64 * 72];
  const int tid = threadIdx.x;
  int id = blockIdx.x;
  if (id < 96) {
    const int kk = id >> 2, w = id & 3;
    const int r = tid >> 2, cq = (tid & 3) * 12;
    const float* sp = Wq + (size_t)(kk * 64 + r) * 192 + w * 48 + cq;
    float4v a = *(const float4v*)(sp);
    float4v b = *(const float4v*)(sp + 4);
    float4v c4 = *(const float4v*)(sp + 8);
    float* dp = wl + r * 52 + cq;
    *(float4v*)(dp) = a; *(float4v*)(dp + 4) = b; *(float4v*)(dp + 8) = c4;
    __syncthreads();
#pragma unroll
    for (int i = 0; i < 2; ++i) {
      const int fid = i * 256 + tid;
      if (fid < 384) {
        const int frag = fid >> 6, lane = fid & 63;
        const int lo = lane & 15, hi = lane >> 4;
        const int c = frag >> 1, ks = frag & 1;
        short8 o;
#pragma unroll
        for (int e = 0; e < 8; ++e)
          o[e] = (short)f2bf(wl[(ks * 32 + hi * 8 + e) * 52 + c * 16 + lo]);
        *(short8*)(Wtf + ((((size_t)kk * 4 + w) * 6 + frag) << 9) + lane * 8) = o;
      }
    }
  } else {
    id -= 96;
    const int r = tid >> 2, cq = (tid & 3) * 16;
    const float* sp = Wo + (size_t)r * 768 + id * 64 + cq;
    float4v v0 = *(const float4v*)(sp);
    float4v v1 = *(const float4v*)(sp + 4);
    float4v v2 = *(const float4v*)(sp + 8);
    float4v v3 = *(const float4v*)(sp + 12);
    short8 s0, s1;
#pragma unroll
    for (int i = 0; i < 4; ++i) {
      s0[i] = (short)f2bf(v0[i]); s0[i + 4] = (short)f2bf(v1[i]);
      s1[i] = (short)f2bf(v2[i]); s1[i + 4] = (short)f2bf(v3[i]);
    }
    *(short8*)(tl + r * 72 + cq) = s0;
    *(short8*)(tl + r * 72 + cq + 8) = s1;
    __syncthreads();
    short8 o0, o1;
#pragma unroll
    for (int j = 0; j < 8; ++j) {
      o0[j] = tl[(cq + j) * 72 + r];
      o1[j] = tl[(cq + 8 + j) * 72 + r];
    }
    short* dp2 = WtO + (size_t)(id * 64 + r) * 64 + cq;
    *(short8*)(dp2) = o0;
    *(short8*)(dp2 + 8) = o1;
  }
}

// ---------------------------------------------------------------------------
// k_qkv: qkv = x @ W_qkv + b; writes fragment-native Qf/Kf/Vf (coalesced).
// 512 blocks x 256 thr (4 waves): block = 32 rows x 192 cols, wave = 32r x 48c.
// r9 loop; K-iteration order rotated per block (phase = blockIdx % 24) so
// concurrent blocks read DIFFERENT W fragments (kills L2 hot-slice storms).
// ---------------------------------------------------------------------------
__global__ __launch_bounds__(256) void k_qkv(
    const float* __restrict__ x, const short* __restrict__ Wtf,
    const float* __restrict__ bq, short* __restrict__ Qf,
    short* __restrict__ Kf, short* __restrict__ Vf) {
  __shared__ __align__(16) short xl[2][32 * 72];
  __shared__ __align__(16) short qbuf[32 * 72], kstg[32 * 72], vstg[32 * 72];
  const int tid = threadIdx.x;
  const int w = tid >> 6, lane = tid & 63, lo = lane & 15, hi = lane >> 4;
  const int m0 = blockIdx.x * 32;
  const int ph = blockIdx.x % 24;          // per-block K-phase rotation
  const float KSC = 0.18033688011112042f;  // (1/8) * log2(e)
  const int cb = w * 48;

  float4v acc[2][3];
#pragma unroll
  for (int r = 0; r < 2; ++r)
#pragma unroll
    for (int c = 0; c < 3; ++c) acc[r][c] = (float4v)0.0f;

  // staging map: thread = (row xr 0..31, col-quad xc); 2 float4 per iter
  const int xr = tid >> 3, xc = (tid & 7) * 8;
  const float* xrow = x + (size_t)(m0 + xr) * 1536 + xc;
  short* xlw0 = &xl[0][xr * 72 + xc];
  short* xlw1 = &xl[1][xr * 72 + xc];

  // Wtf base for this wave: frag (kk, c, ks) at wbase + kk*12288 + (c*2+ks)*512
  const short* wbase = Wtf + ((size_t)w * 6) * 512 + lane * 8;

  int kkE = ph;  // effective (rotated) K index for this iteration
  float4v xv0 = *(const float4v*)(xrow + kkE * 64 + 0);
  float4v xv1 = *(const float4v*)(xrow + kkE * 64 + 4);
  short8 bcur[3][2];
  {
    const short* wp = wbase + (size_t)kkE * 12288;
#pragma unroll
    for (int c = 0; c < 3; ++c)
#pragma unroll
      for (int ks = 0; ks < 2; ++ks)
        bcur[c][ks] = ldg8(wp + (c * 2 + ks) * 512);
  }
  {
    short8 s0;
#pragma unroll
    for (int i = 0; i < 4; ++i) { s0[i] = (short)f2bf(xv0[i]); s0[i + 4] = (short)f2bf(xv1[i]); }
    *(short8*)(xlw0) = s0;
  }
  LDS_BARRIER();

  for (int kk = 0; kk < 24; ++kk) {
    const int cur = kk & 1;
    const int kkN = (kkE + 1 == 24) ? 0 : kkE + 1;
    short8 bnxt[3][2];
    if (kk < 23) {
      xv0 = *(const float4v*)(xrow + kkN * 64 + 0);
      xv1 = *(const float4v*)(xrow + kkN * 64 + 4);
      const short* wn = wbase + (size_t)kkN * 12288;
#pragma unroll
      for (int c = 0; c < 3; ++c)
#pragma unroll
        for (int ks = 0; ks < 2; ++ks)
          bnxt[c][ks] = ldg8(wn + (c * 2 + ks) * 512);
    }
    const short* xb = &xl[cur][0];
#pragma unroll
    for (int r = 0; r < 2; ++r) {
      short8 a0 = *(const short8*)(xb + (r * 16 + lo) * 72 + hi * 8);
      short8 a1 = *(const short8*)(xb + (r * 16 + lo) * 72 + 32 + hi * 8);
#pragma unroll
      for (int c = 0; c < 3; ++c) {
        acc[r][c] = MFMA16(a0, bcur[c][0], acc[r][c]);
        acc[r][c] = MFMA16(a1, bcur[c][1], acc[r][c]);
      }
    }
    if (kk < 23) {
      short8 s0;
#pragma unroll
      for (int i = 0; i < 4; ++i) { s0[i] = (short)f2bf(xv0[i]); s0[i + 4] = (short)f2bf(xv1[i]); }
      *(short8*)(cur ? xlw0 : xlw1) = s0;
#pragma unroll
      for (int c = 0; c < 3; ++c) { bcur[c][0] = bnxt[c][0]; bcur[c][1] = bnxt[c][1]; }
    }
    LDS_BARRIER();
    kkE = kkN;
  }

  float bb[3];
#pragma unroll
  for (int c = 0; c < 3; ++c) bb[c] = bq[cb + c * 16 + lo];

  const int b = m0 >> 11;
  const int row0 = m0 & 2047;  // batch-local 32-aligned row of block start

#pragma unroll
  for (int r = 0; r < 2; ++r)
#pragma unroll
    for (int c = 0; c < 3; ++c) {
      const int colb = cb + c * 16;
      short* buf = (colb < 64) ? qbuf : ((colb < 128) ? kstg : vstg);
      const int d0 = (colb & 63) + lo;
#pragma unroll
      for (int j = 0; j < 4; ++j) {
        float vv = acc[r][c][j] + bb[c];
        if (colb < 64) vv *= KSC;  // q: fold softmax scale (exp2 domain)
        buf[(r * 16 + hi * 4 + j) * 72 + d0] = (short)f2bf(vv);
      }
    }
  LDS_BARRIER();

  // Q/K fragment stores: thread = (row rr 0..31, 8-d group dq)
  {
    const int rr = tid >> 3, dq = (tid & 7) * 8;
    const int t32 = row0 >> 5, i = dq >> 4, h = (dq >> 3) & 1;
    const size_t base = ((((size_t)b * 64 + t32) * 4 + i) * 2 + h) * 256 + rr * 8;
    *(short8*)(Qf + base) = *(const short8*)(qbuf + rr * 72 + dq);
    *(short8*)(Kf + base) = *(const short8*)(kstg + rr * 72 + dq);
  }

  // V fragment store: thread = (d=dr 0..63, 8-key group kq8), LDS transpose
  {
    const int dr = tid >> 2, kq8 = (tid & 3) * 8;
    short8 o0;
#pragma unroll
    for (int j = 0; j < 8; ++j) o0[j] = vstg[(kq8 + j) * 72 + dr];
    const int kg = row0 >> 5, s = (kq8 >> 4) & 1, h = (kq8 >> 3) & 1;
    const int dc = dr >> 5, c32 = dr & 31;
    short* vp = Vf + ((((((size_t)b * 64 + kg) * 2 + dc) * 2 + s) * 2 + h) * 32 + c32) * 8;
    *(short8*)(vp) = o0;
  }
}

// ---------------------------------------------------------------------------
// k_attn: in-block split-K flash attn. 512 blocks x 512 thr (8 waves).
// Subtile order rotated by qg&7 so blocks sharing a batch read different
// K/V lines at any instant.
// ---------------------------------------------------------------------------
__global__ __launch_bounds__(512) void k_attn(
    const short* __restrict__ Qf, const short* __restrict__ Kf,
    const short* __restrict__ Vf, short* __restrict__ att) {
  __shared__ float Od[8][32][76];
  __shared__ float Ol[8][32];
  const int tid = threadIdx.x;
  const int w = tid >> 6, lane = tid & 63;
  const int c = lane & 31, h = lane >> 5;
  const int b = blockIdx.x >> 6;
  const int qg = blockIdx.x & 63;
  const int rot = qg & 7;
  const size_t g0 = (size_t)b * 2048 + qg * 32;

  short8 qf0 = ldg8(Qf + (((size_t)b * 64 + qg) * 4 + 0) * 512 + lane * 8);
  short8 qf1 = ldg8(Qf + (((size_t)b * 64 + qg) * 4 + 1) * 512 + lane * 8);
  short8 qf2 = ldg8(Qf + (((size_t)b * 64 + qg) * 4 + 2) * 512 + lane * 8);
  short8 qf3 = ldg8(Qf + (((size_t)b * 64 + qg) * 4 + 3) * 512 + lane * 8);

  float lp = 0.0f;
  float16v acc0 = (float16v)0.0f;   // O^T d 0..31
  float16v acc1 = (float16v)0.0f;   // O^T d 32..63

  const short* kb = Kf + ((size_t)b * 64) * 2048 + lane * 8;
  const short* vb = Vf + ((size_t)b * 64) * 2048 + lane * 8;
  // wave w owns subtiles w*8 + ((rot + t) & 7), t = 0..7
#define KGI(T) (w * 8 + ((rot + (T)) & 7))

#define ATTN_STEP(K0, K1, K2, K3, V0, V1, V2, V3)                              \
  do {                                                                         \
    float16v sf = (float16v)0.0f;                                              \
    sf = MFMA32(K0, qf0, sf);                                                  \
    sf = MFMA32(K1, qf1, sf);                                                  \
    sf = MFMA32(K2, qf2, sf);                                                  \
    sf = MFMA32(K3, qf3, sf);                                                  \
    unsigned wpk[8];                                                           \
    _Pragma("unroll")                                                          \
    for (int m = 0; m < 8; ++m) {                                              \
      float p0 = __builtin_amdgcn_exp2f(sf[2 * m]);                            \
      float p1 = __builtin_amdgcn_exp2f(sf[2 * m + 1]);                        \
      unsigned u0 = __builtin_bit_cast(unsigned, p0) & 0xFFFF0000u;            \
      unsigned u1 = __builtin_bit_cast(unsigned, p1) & 0xFFFF0000u;            \
      lp += __builtin_bit_cast(float, u0) + __builtin_bit_cast(float, u1);     \
      wpk[m] = (u0 >> 16) | u1;                                                \
    }                                                                          \
    plswap(wpk[0], wpk[2]);                                                    \
    plswap(wpk[1], wpk[3]);                                                    \
    plswap(wpk[4], wpk[6]);                                                    \
    plswap(wpk[5], wpk[7]);                                                    \
    union { unsigned u[4]; short8 s8; } bt0, bt1;                              \
    bt0.u[0] = wpk[0]; bt0.u[1] = wpk[1]; bt0.u[2] = wpk[2]; bt0.u[3] = wpk[3];\
    bt1.u[0] = wpk[4]; bt1.u[1] = wpk[5]; bt1.u[2] = wpk[6]; bt1.u[3] = wpk[7];\
    acc0 = MFMA32(V0, bt0.s8, acc0);                                           \
    acc0 = MFMA32(V1, bt1.s8, acc0);                                           \
    acc1 = MFMA32(V2, bt0.s8, acc1);                                           \
    acc1 = MFMA32(V3, bt1.s8, acc1);                                           \
  } while (0)

  {
    const int kgA = KGI(0);
    const short* kpA = kb + (size_t)kgA * 2048;
    const short* vpA = vb + (size_t)kgA * 2048;
    short8 ka0 = ldg8(kpA), ka1 = ldg8(kpA + 512), ka2 = ldg8(kpA + 1024), ka3 = ldg8(kpA + 1536);
    short8 va0 = ldg8(vpA), va1 = ldg8(vpA + 512), va2 = ldg8(vpA + 1024), va3 = ldg8(vpA + 1536);

    for (int t = 0; t < 8; t += 2) {
      const int kgB = KGI(t + 1);
      const short* kpB = kb + (size_t)kgB * 2048;
      const short* vpB = vb + (size_t)kgB * 2048;
      short8 kb0 = ldg8(kpB), kb1 = ldg8(kpB + 512), kb2 = ldg8(kpB + 1024), kb3 = ldg8(kpB + 1536);
      short8 vb0 = ldg8(vpB), vb1 = ldg8(vpB + 512), vb2 = ldg8(vpB + 1024), vb3 = ldg8(vpB + 1536);

      ATTN_STEP(ka0, ka1, ka2, ka3, va0, va1, va2, va3);

      if (t + 2 < 8) {
        const int kgN = KGI(t + 2);
        const short* kpN = kb + (size_t)kgN * 2048;
        const short* vpN = vb + (size_t)kgN * 2048;
        ka0 = ldg8(kpN); ka1 = ldg8(kpN + 512); ka2 = ldg8(kpN + 1024); ka3 = ldg8(kpN + 1536);
        va0 = ldg8(vpN); va1 = ldg8(vpN + 512); va2 = ldg8(vpN + 1024); va3 = ldg8(vpN + 1536);
      }

      ATTN_STEP(kb0, kb1, kb2, kb3, vb0, vb1, vb2, vb3);
    }
  }
#undef ATTN_STEP
#undef KGI

  lp += __shfl_xor(lp, 32, 64);

#pragma unroll
  for (int g = 0; g < 4; ++g) {
    float4v a0, a1;
#pragma unroll
    for (int r = 0; r < 4; ++r) { a0[r] = acc0[4 * g + r]; a1[r] = acc1[4 * g + r]; }
    *(float4v*)(&Od[w][c][8 * g + 4 * h]) = a0;
    *(float4v*)(&Od[w][c][32 + 8 * g + 4 * h]) = a1;
  }
  if (h == 0) Ol[w][c] = lp;
  __syncthreads();

  {
    const int q = tid >> 4, dq = (tid & 15) * 4;
    float L = 0.0f;
    float4v o = (float4v)0.0f;
#pragma unroll
    for (int w2 = 0; w2 < 8; ++w2) {
      L += Ol[w2][q];
      o += *(const float4v*)(&Od[w2][q][dq]);
    }
    const float inv = 1.0f / L;
    short4v r;
#pragma unroll
    for (int j = 0; j < 4; ++j) r[j] = (short)f2bf(o[j] * inv);
    *(short4v*)(att + (g0 + q) * 64 + dq) = r;
  }
}

// ---------------------------------------------------------------------------
// k_out: out = att @ W_out + b_out (fp32 out). 512 blocks x 256 thr (4 waves).
// Column order rotated by blockIdx%12 (addresses only; acc statically indexed).
// ---------------------------------------------------------------------------
__global__ __launch_bounds__(256) void k_out(
    const short* __restrict__ att, const short* __restrict__ WtO,
    const float* __restrict__ bo, float* __restrict__ out) {
  const int tid = threadIdx.x;
  const int w = tid >> 6, lane = tid & 63, lo = lane & 15, hi = lane >> 4;
  const int wc = w * 192;
  const int m0 = blockIdx.x * 32;
  const int crot = blockIdx.x % 12;

  short8 af[2][2];
#pragma unroll
  for (int rf = 0; rf < 2; ++rf) {
    const short* ap = att + (size_t)(m0 + rf * 16 + lo) * 64 + hi * 8;
    af[rf][0] = ldg8(ap);
    af[rf][1] = ldg8(ap + 32);
  }
  float4v acc[2][12];
#pragma unroll
  for (int rf = 0; rf < 2; ++rf)
#pragma unroll
    for (int c = 0; c < 12; ++c) acc[rf][c] = (float4v)0.0f;

#pragma unroll
  for (int cc = 0; cc < 12; ++cc) {
    const int c = (cc + crot >= 12) ? cc + crot - 12 : cc + crot;
    const short* bp = WtO + (size_t)(wc + c * 16 + lo) * 64 + hi * 8;
    short8 b0 = ldg8(bp);
    short8 b1 = ldg8(bp + 32);
#pragma unroll
    for (int rf = 0; rf < 2; ++rf) {
      acc[rf][cc] = MFMA16(af[rf][0], b0, acc[rf][cc]);
      acc[rf][cc] = MFMA16(af[rf][1], b1, acc[rf][cc]);
    }
  }
#pragma unroll
  for (int cc = 0; cc < 12; ++cc) {
    const int c = (cc + crot >= 12) ? cc + crot - 12 : cc + crot;
    const float bb = bo[wc + c * 16 + lo];
#pragma unroll
    for (int rf = 0; rf < 2; ++rf)
#pragma unroll
      for (int j = 0; j < 4; ++j)
        out[(size_t)(m0 + rf * 16 + hi * 4 + j) * 768 + wc + c * 16 + lo] =
            acc[rf][cc][j] + bb;
  }
}

extern "C" void kernel_launch(void* const* d_in, const int* in_sizes, int n_in,
                              void* d_out, int out_size, void* d_ws, size_t ws_size,
                              hipStream_t stream) {
  (void)in_sizes; (void)n_in; (void)out_size; (void)ws_size;
  const float* x  = (const float*)d_in[0];
  const float* Wq = (const float*)d_in[1];
  const float* bq = (const float*)d_in[2];
  const float* Wo = (const float*)d_in[3];
  const float* bo = (const float*)d_in[4];
  float* out = (float*)d_out;

  char* ws = (char*)d_ws;
  short* Qf  = (short*)(ws);
  short* Kf  = (short*)(ws + 2097152);
  short* Vf  = (short*)(ws + 4194304);
  short* att = (short*)(ws + 6291456);
  short* Wtf = (short*)(ws + 8388608);
  short* WtO = (short*)(ws + 8978432);

  k_prep<<<108, 256, 0, stream>>>(Wq, Wo, Wtf, WtO);
  k_qkv<<<512, 256, 0, stream>>>(x, Wtf, bq, Qf, Kf, Vf);
  k_attn<<<512, 512, 0, stream>>>(Qf, Kf, Vf, att);
  k_out<<<512, 256, 0, stream>>>(att, WtO, bo, out);
}

// Round 19
// 59.973 us; speedup vs baseline: 1.1121x; 1.0581x over previous
//
#include <hip/hip_runtime.h>
#include <hip/hip_bf16.h>

// TinyAttention fused pipeline, bf16 MFMA path.
// Round 19: base = round 15 (61.8us best). k_attn and k_out fused into one
// kernel (same 512-block/32-row decomposition): combine writes the att tile
// into LDS (overlaying Od after an extra barrier; 2 blocks/CU preserved) and
// the out-GEMM runs as phase 2 (8 waves x 96 cols). Deletes the 2MB att
// write + 2MB read + one launch. k_qkv is closed at ~41us (236 TF == the
// 2-barrier-per-K-step structure's measured envelope at this problem scale;
// 10 structural hypotheses tested null across rounds 9-18).
// ws layout (bytes):
//   Qf  bf16 [8][64][4][2][32][8]    @ 0         (2,097,152)  (q pre-scaled)
//   Kf  bf16 [8][64][4][2][32][8]    @ 2,097,152 (2,097,152)
//   Vf  bf16 [8][64][2][2][2][32][8] @ 4,194,304 (2,097,152)
//   (att buffer slot unused after fusion)
//   Wtf bf16 [24][4][6][64][8]       @ 8,388,608 (589,824)   (frag-native)
//   WtO bf16 [768][64]               @ 8,978,432 (98,304)

typedef __attribute__((ext_vector_type(8))) short short8;
typedef __attribute__((ext_vector_type(4))) short short4v;
typedef __attribute__((ext_vector_type(4))) float float4v;
typedef __attribute__((ext_vector_type(16))) float float16v;

#define MFMA16(a, b, c) __builtin_amdgcn_mfma_f32_16x16x32_bf16((a), (b), (c), 0, 0, 0)
#define MFMA32(a, b, c) __builtin_amdgcn_mfma_f32_32x32x16_bf16((a), (b), (c), 0, 0, 0)

// LDS-only barrier: orders ds ops across the block without draining vmcnt.
#define LDS_BARRIER() asm volatile("s_waitcnt lgkmcnt(0)\n\ts_barrier" ::: "memory")

// v_permlane32_swap_b32 a, b:  a[32+i] <-> b[i]  (VALU cross-lane, no DS)
static __device__ __forceinline__ void plswap(unsigned& a, unsigned& b) {
  asm("v_permlane32_swap_b32 %0, %1" : "+v"(a), "+v"(b));
}

static __device__ __forceinline__ unsigned short f2bf(float x) {
  union { float f; unsigned u; } v; v.f = x;
  return (unsigned short)((v.u + 0x7FFFu + ((v.u >> 16) & 1u)) >> 16);
}
static __device__ __forceinline__ short8 ldg8(const short* p) {
  return *(const short8*)p;
}

// ---------------------------------------------------------------------------
// k_prep:
//  blocks 0..95 : W_qkv f32 [1536][192] -> Wtf bf16 fragment-native
//  blocks 96..107: W_out f32 [64][768] -> WtO bf16 [768][64]
// ---------------------------------------------------------------------------
__global__ __launch_bounds__(256) void k_prep(
    const float* __restrict__ Wq, const float* __restrict__ Wo,
    short* __restrict__ Wtf, short* __restrict__ WtO) {
  __shared__ float wl[64 * 52];
  __shared__ __align__(16) short tl[64 * 72];
  const int tid = threadIdx.x;
  int id = blockIdx.x;
  if (id < 96) {
    const int kk = id >> 2, w = id & 3;
    const int r = tid >> 2, cq = (tid & 3) * 12;
    const float* sp = Wq + (size_t)(kk * 64 + r) * 192 + w * 48 + cq;
    float4v a = *(const float4v*)(sp);
    float4v b = *(const float4v*)(sp + 4);
    float4v c4 = *(const float4v*)(sp + 8);
    float* dp = wl + r * 52 + cq;
    *(float4v*)(dp) = a; *(float4v*)(dp + 4) = b; *(float4v*)(dp + 8) = c4;
    __syncthreads();
#pragma unroll
    for (int i = 0; i < 2; ++i) {
      const int fid = i * 256 + tid;
      if (fid < 384) {
        const int frag = fid >> 6, lane = fid & 63;
        const int lo = lane & 15, hi = lane >> 4;
        const int c = frag >> 1, ks = frag & 1;
        short8 o;
#pragma unroll
        for (int e = 0; e < 8; ++e)
          o[e] = (short)f2bf(wl[(ks * 32 + hi * 8 + e) * 52 + c * 16 + lo]);
        *(short8*)(Wtf + ((((size_t)kk * 4 + w) * 6 + frag) << 9) + lane * 8) = o;
      }
    }
  } else {
    id -= 96;
    const int r = tid >> 2, cq = (tid & 3) * 16;
    const float* sp = Wo + (size_t)r * 768 + id * 64 + cq;
    float4v v0 = *(const float4v*)(sp);
    float4v v1 = *(const float4v*)(sp + 4);
    float4v v2 = *(const float4v*)(sp + 8);
    float4v v3 = *(const float4v*)(sp + 12);
    short8 s0, s1;
#pragma unroll
    for (int i = 0; i < 4; ++i) {
      s0[i] = (short)f2bf(v0[i]); s0[i + 4] = (short)f2bf(v1[i]);
      s1[i] = (short)f2bf(v2[i]); s1[i + 4] = (short)f2bf(v3[i]);
    }
    *(short8*)(tl + r * 72 + cq) = s0;
    *(short8*)(tl + r * 72 + cq + 8) = s1;
    __syncthreads();
    short8 o0, o1;
#pragma unroll
    for (int j = 0; j < 8; ++j) {
      o0[j] = tl[(cq + j) * 72 + r];
      o1[j] = tl[(cq + 8 + j) * 72 + r];
    }
    short* dp2 = WtO + (size_t)(id * 64 + r) * 64 + cq;
    *(short8*)(dp2) = o0;
    *(short8*)(dp2 + 8) = o1;
  }
}

// ---------------------------------------------------------------------------
// k_qkv: qkv = x @ W_qkv + b; writes fragment-native Qf/Kf/Vf (coalesced).
// 512 blocks x 256 thr (4 waves): block = 32 rows x 192 cols, wave = 32r x 48c.
// r9 structure, lgkmcnt-only barriers (r15 best).
// ---------------------------------------------------------------------------
__global__ __launch_bounds__(256) void k_qkv(
    const float* __restrict__ x, const short* __restrict__ Wtf,
    const float* __restrict__ bq, short* __restrict__ Qf,
    short* __restrict__ Kf, short* __restrict__ Vf) {
  __shared__ __align__(16) short xl[2][32 * 72];
  __shared__ __align__(16) short qbuf[32 * 72], kstg[32 * 72], vstg[32 * 72];
  const int tid = threadIdx.x;
  const int w = tid >> 6, lane = tid & 63, lo = lane & 15, hi = lane >> 4;
  const int m0 = blockIdx.x * 32;
  const float KSC = 0.18033688011112042f;  // (1/8) * log2(e)
  const int cb = w * 48;

  float4v acc[2][3];
#pragma unroll
  for (int r = 0; r < 2; ++r)
#pragma unroll
    for (int c = 0; c < 3; ++c) acc[r][c] = (float4v)0.0f;

  const int xr = tid >> 3, xc = (tid & 7) * 8;
  const float* xrow = x + (size_t)(m0 + xr) * 1536 + xc;
  short* xlw0 = &xl[0][xr * 72 + xc];
  short* xlw1 = &xl[1][xr * 72 + xc];

  const short* wbase = Wtf + ((size_t)w * 6) * 512 + lane * 8;

  float4v xv0 = *(const float4v*)(xrow + 0);
  float4v xv1 = *(const float4v*)(xrow + 4);
  short8 bcur[3][2];
#pragma unroll
  for (int c = 0; c < 3; ++c)
#pragma unroll
    for (int ks = 0; ks < 2; ++ks)
      bcur[c][ks] = ldg8(wbase + (c * 2 + ks) * 512);
  {
    short8 s0;
#pragma unroll
    for (int i = 0; i < 4; ++i) { s0[i] = (short)f2bf(xv0[i]); s0[i + 4] = (short)f2bf(xv1[i]); }
    *(short8*)(xlw0) = s0;
  }
  LDS_BARRIER();

  for (int kk = 0; kk < 24; ++kk) {
    const int cur = kk & 1;
    short8 bnxt[3][2];
    if (kk < 23) {
      const int k1 = (kk + 1) * 64;
      xv0 = *(const float4v*)(xrow + k1 + 0);
      xv1 = *(const float4v*)(xrow + k1 + 4);
      const short* wn = wbase + (size_t)(kk + 1) * 12288;
#pragma unroll
      for (int c = 0; c < 3; ++c)
#pragma unroll
        for (int ks = 0; ks < 2; ++ks)
          bnxt[c][ks] = ldg8(wn + (c * 2 + ks) * 512);
    }
    const short* xb = &xl[cur][0];
#pragma unroll
    for (int r = 0; r < 2; ++r) {
      short8 a0 = *(const short8*)(xb + (r * 16 + lo) * 72 + hi * 8);
      short8 a1 = *(const short8*)(xb + (r * 16 + lo) * 72 + 32 + hi * 8);
#pragma unroll
      for (int c = 0; c < 3; ++c) {
        acc[r][c] = MFMA16(a0, bcur[c][0], acc[r][c]);
        acc[r][c] = MFMA16(a1, bcur[c][1], acc[r][c]);
      }
    }
    if (kk < 23) {
      short8 s0;
#pragma unroll
      for (int i = 0; i < 4; ++i) { s0[i] = (short)f2bf(xv0[i]); s0[i + 4] = (short)f2bf(xv1[i]); }
      *(short8*)(cur ? xlw0 : xlw1) = s0;
#pragma unroll
      for (int c = 0; c < 3; ++c) { bcur[c][0] = bnxt[c][0]; bcur[c][1] = bnxt[c][1]; }
    }
    LDS_BARRIER();
  }

  float bb[3];
#pragma unroll
  for (int c = 0; c < 3; ++c) bb[c] = bq[cb + c * 16 + lo];

  const int b = m0 >> 11;
  const int row0 = m0 & 2047;

#pragma unroll
  for (int r = 0; r < 2; ++r)
#pragma unroll
    for (int c = 0; c < 3; ++c) {
      const int colb = cb + c * 16;
      short* buf = (colb < 64) ? qbuf : ((colb < 128) ? kstg : vstg);
      const int d0 = (colb & 63) + lo;
#pragma unroll
      for (int j = 0; j < 4; ++j) {
        float vv = acc[r][c][j] + bb[c];
        if (colb < 64) vv *= KSC;  // q: fold softmax scale (exp2 domain)
        buf[(r * 16 + hi * 4 + j) * 72 + d0] = (short)f2bf(vv);
      }
    }
  LDS_BARRIER();

  // Q/K fragment stores: thread = (row rr 0..31, 8-d group dq)
  {
    const int rr = tid >> 3, dq = (tid & 7) * 8;
    const int t32 = row0 >> 5, i = dq >> 4, h = (dq >> 3) & 1;
    const size_t base = ((((size_t)b * 64 + t32) * 4 + i) * 2 + h) * 256 + rr * 8;
    *(short8*)(Qf + base) = *(const short8*)(qbuf + rr * 72 + dq);
    *(short8*)(Kf + base) = *(const short8*)(kstg + rr * 72 + dq);
  }

  // V fragment store: thread = (d=dr 0..63, 8-key group kq8), LDS transpose
  {
    const int dr = tid >> 2, kq8 = (tid & 3) * 8;
    short8 o0;
#pragma unroll
    for (int j = 0; j < 8; ++j) o0[j] = vstg[(kq8 + j) * 72 + dr];
    const int kg = row0 >> 5, s = (kq8 >> 4) & 1, h = (kq8 >> 3) & 1;
    const int dc = dr >> 5, c32 = dr & 31;
    short* vp = Vf + ((((((size_t)b * 64 + kg) * 2 + dc) * 2 + s) * 2 + h) * 32 + c32) * 8;
    *(short8*)(vp) = o0;
  }
}

// ---------------------------------------------------------------------------
// k_attnout: fused flash-attention + output GEMM. 512 blocks x 512 thr.
// Phase 1 (8 waves, in-block split-K attn, LDS f32 combine) -> att tile in
// LDS (overlays Od after reads complete). Phase 2: out = att @ W_out + b_out
// (8 waves x 96 cols each, att A-frags via ds_read).
// ---------------------------------------------------------------------------
__global__ __launch_bounds__(512) void k_attnout(
    const short* __restrict__ Qf, const short* __restrict__ Kf,
    const short* __restrict__ Vf, const short* __restrict__ WtO,
    const float* __restrict__ bo, float* __restrict__ out) {
  __shared__ __align__(16) float Od[8][32][76];
  __shared__ float Ol[8][32];
  const int tid = threadIdx.x;
  const int w = tid >> 6, lane = tid & 63;
  const int c = lane & 31, h = lane >> 5;
  const int lo = lane & 15, hi = lane >> 4;
  const int b = blockIdx.x >> 6;
  const int qg = blockIdx.x & 63;
  const int m0 = blockIdx.x * 32;   // global row base (== b*2048 + qg*32)

  short8 qf0 = ldg8(Qf + (((size_t)b * 64 + qg) * 4 + 0) * 512 + lane * 8);
  short8 qf1 = ldg8(Qf + (((size_t)b * 64 + qg) * 4 + 1) * 512 + lane * 8);
  short8 qf2 = ldg8(Qf + (((size_t)b * 64 + qg) * 4 + 2) * 512 + lane * 8);
  short8 qf3 = ldg8(Qf + (((size_t)b * 64 + qg) * 4 + 3) * 512 + lane * 8);

  float lp = 0.0f;
  float16v acc0 = (float16v)0.0f;   // O^T d 0..31
  float16v acc1 = (float16v)0.0f;   // O^T d 32..63

  int kg = w * 8;                   // 8 subtiles of 32 keys = 256 keys/wave
  const short* kb = Kf + ((size_t)b * 64) * 2048 + lane * 8;
  const short* vb = Vf + ((size_t)b * 64) * 2048 + lane * 8;

#define ATTN_STEP(K0, K1, K2, K3, V0, V1, V2, V3)                              \
  do {                                                                         \
    float16v sf = (float16v)0.0f;                                              \
    sf = MFMA32(K0, qf0, sf);                                                  \
    sf = MFMA32(K1, qf1, sf);                                                  \
    sf = MFMA32(K2, qf2, sf);                                                  \
    sf = MFMA32(K3, qf3, sf);                                                  \
    unsigned wpk[8];                                                           \
    _Pragma("unroll")                                                          \
    for (int m = 0; m < 8; ++m) {                                              \
      float p0 = __builtin_amdgcn_exp2f(sf[2 * m]);                            \
      float p1 = __builtin_amdgcn_exp2f(sf[2 * m + 1]);                        \
      unsigned u0 = __builtin_bit_cast(unsigned, p0) & 0xFFFF0000u;            \
      unsigned u1 = __builtin_bit_cast(unsigned, p1) & 0xFFFF0000u;            \
      lp += __builtin_bit_cast(float, u0) + __builtin_bit_cast(float, u1);     \
      wpk[m] = (u0 >> 16) | u1;                                                \
    }                                                                          \
    plswap(wpk[0], wpk[2]);                                                    \
    plswap(wpk[1], wpk[3]);                                                    \
    plswap(wpk[4], wpk[6]);                                                    \
    plswap(wpk[5], wpk[7]);                                                    \
    union { unsigned u[4]; short8 s8; } bt0, bt1;                              \
    bt0.u[0] = wpk[0]; bt0.u[1] = wpk[1]; bt0.u[2] = wpk[2]; bt0.u[3] = wpk[3];\
    bt1.u[0] = wpk[4]; bt1.u[1] = wpk[5]; bt1.u[2] = wpk[6]; bt1.u[3] = wpk[7];\
    acc0 = MFMA32(V0, bt0.s8, acc0);                                           \
    acc0 = MFMA32(V1, bt1.s8, acc0);                                           \
    acc1 = MFMA32(V2, bt0.s8, acc1);                                           \
    acc1 = MFMA32(V3, bt1.s8, acc1);                                           \
  } while (0)

  const short* kpA = kb + (size_t)kg * 2048;
  const short* vpA = vb + (size_t)kg * 2048;
  short8 ka0 = ldg8(kpA), ka1 = ldg8(kpA + 512), ka2 = ldg8(kpA + 1024), ka3 = ldg8(kpA + 1536);
  short8 va0 = ldg8(vpA), va1 = ldg8(vpA + 512), va2 = ldg8(vpA + 1024), va3 = ldg8(vpA + 1536);

  for (int t = 0; t < 8; t += 2) {
    const short* kpB = kb + (size_t)(kg + 1) * 2048;
    const short* vpB = vb + (size_t)(kg + 1) * 2048;
    short8 kb0 = ldg8(kpB), kb1 = ldg8(kpB + 512), kb2 = ldg8(kpB + 1024), kb3 = ldg8(kpB + 1536);
    short8 vb0 = ldg8(vpB), vb1 = ldg8(vpB + 512), vb2 = ldg8(vpB + 1024), vb3 = ldg8(vpB + 1536);

    ATTN_STEP(ka0, ka1, ka2, ka3, va0, va1, va2, va3);

    if (t + 2 < 8) {
      const short* kpN = kb + (size_t)(kg + 2) * 2048;
      const short* vpN = vb + (size_t)(kg + 2) * 2048;
      ka0 = ldg8(kpN); ka1 = ldg8(kpN + 512); ka2 = ldg8(kpN + 1024); ka3 = ldg8(kpN + 1536);
      va0 = ldg8(vpN); va1 = ldg8(vpN + 512); va2 = ldg8(vpN + 1024); va3 = ldg8(vpN + 1536);
    }

    ATTN_STEP(kb0, kb1, kb2, kb3, vb0, vb1, vb2, vb3);
    kg += 2;
  }
#undef ATTN_STEP

  lp += __shfl_xor(lp, 32, 64);

  // write wave partials to LDS
#pragma unroll
  for (int g = 0; g < 4; ++g) {
    float4v a0, a1;
#pragma unroll
    for (int r = 0; r < 4; ++r) { a0[r] = acc0[4 * g + r]; a1[r] = acc1[4 * g + r]; }
    *(float4v*)(&Od[w][c][8 * g + 4 * h]) = a0;
    *(float4v*)(&Od[w][c][32 + 8 * g + 4 * h]) = a1;
  }
  if (h == 0) Ol[w][c] = lp;
  __syncthreads();

  // combine 8 wave-partials into registers: thread = (q = tid>>4, dq quad)
  short4v attr;
  {
    const int q = tid >> 4, dq = (tid & 15) * 4;
    float L = 0.0f;
    float4v o = (float4v)0.0f;
#pragma unroll
    for (int w2 = 0; w2 < 8; ++w2) {
      L += Ol[w2][q];
      o += *(const float4v*)(&Od[w2][q][dq]);
    }
    const float inv = 1.0f / L;
#pragma unroll
    for (int j = 0; j < 4; ++j) attr[j] = (short)f2bf(o[j] * inv);
  }
  __syncthreads();  // all Od reads done before overwrite

  // att tile [32][72] bf16 overlays Od storage
  short* attL = (short*)&Od[0][0][0];
  {
    const int q = tid >> 4, dq = (tid & 15) * 4;
    *(short4v*)(attL + q * 72 + dq) = attr;
  }
  LDS_BARRIER();

  // ---- phase 2: out[m0..m0+32) = att @ W_out + b_out; wave w: 96 cols ----
  const int wc = w * 96;
  short8 af[2][2];
#pragma unroll
  for (int rf = 0; rf < 2; ++rf) {
    af[rf][0] = *(const short8*)(attL + (rf * 16 + lo) * 72 + hi * 8);
    af[rf][1] = *(const short8*)(attL + (rf * 16 + lo) * 72 + 32 + hi * 8);
  }
  float4v oacc[2][6];
#pragma unroll
  for (int rf = 0; rf < 2; ++rf)
#pragma unroll
    for (int cc = 0; cc < 6; ++cc) oacc[rf][cc] = (float4v)0.0f;

#pragma unroll
  for (int cc = 0; cc < 6; ++cc) {
    const short* bp = WtO + (size_t)(wc + cc * 16 + lo) * 64 + hi * 8;
    short8 b0 = ldg8(bp);
    short8 b1 = ldg8(bp + 32);
#pragma unroll
    for (int rf = 0; rf < 2; ++rf) {
      oacc[rf][cc] = MFMA16(af[rf][0], b0, oacc[rf][cc]);
      oacc[rf][cc] = MFMA16(af[rf][1], b1, oacc[rf][cc]);
    }
  }
#pragma unroll
  for (int cc = 0; cc < 6; ++cc) {
    const float bb = bo[wc + cc * 16 + lo];
#pragma unroll
    for (int rf = 0; rf < 2; ++rf)
#pragma unroll
      for (int j = 0; j < 4; ++j)
        out[(size_t)(m0 + rf * 16 + hi * 4 + j) * 768 + wc + cc * 16 + lo] =
            oacc[rf][cc][j] + bb;
  }
}

extern "C" void kernel_launch(void* const* d_in, const int* in_sizes, int n_in,
                              void* d_out, int out_size, void* d_ws, size_t ws_size,
                              hipStream_t stream) {
  (void)in_sizes; (void)n_in; (void)out_size; (void)ws_size;
  const float* x  = (const float*)d_in[0];
  const float* Wq = (const float*)d_in[1];
  const float* bq = (const float*)d_in[2];
  const float* Wo = (const float*)d_in[3];
  const float* bo = (const float*)d_in[4];
  float* out = (float*)d_out;

  char* ws = (char*)d_ws;
  short* Qf  = (short*)(ws);
  short* Kf  = (short*)(ws + 2097152);
  short* Vf  = (short*)(ws + 4194304);
  short* Wtf = (short*)(ws + 8388608);
  short* WtO = (short*)(ws + 8978432);

  k_prep<<<108, 256, 0, stream>>>(Wq, Wo, Wtf, WtO);
  k_qkv<<<512, 256, 0, stream>>>(x, Wtf, bq, Qf, Kf, Vf);
  k_attnout<<<512, 512, 0, stream>>>(Qf, Kf, Vf, WtO, bo, out);
}